// Round 3
// baseline (91.892 us; speedup 1.0000x reference)
//
#include <hip/hip_runtime.h>
#include <hip/hip_bf16.h>
#include <math.h>

#define BDIM 512
#define DDIM 512
#define SPLIT 4     // blocks per row in pair_loss
#define NPART (BDIM * SPLIT)

typedef __attribute__((ext_vector_type(8))) short bfrag;   // 8 bf16 = 4 VGPRs
typedef __attribute__((ext_vector_type(4))) float ffrag;   // 4 fp32 acc

// Convert 8 consecutive fp32 -> bf16 MFMA fragment, in registers.
__device__ __forceinline__ bfrag cvt8(const float* __restrict__ p) {
    float4 a = *(const float4*)p;
    float4 b = *(const float4*)(p + 4);
    union { __hip_bfloat16 h[8]; bfrag f; } u;
    u.h[0] = __float2bfloat16(a.x); u.h[1] = __float2bfloat16(a.y);
    u.h[2] = __float2bfloat16(a.z); u.h[3] = __float2bfloat16(a.w);
    u.h[4] = __float2bfloat16(b.x); u.h[5] = __float2bfloat16(b.y);
    u.h[6] = __float2bfloat16(b.z); u.h[7] = __float2bfloat16(b.w);
    return u.f;
}

// ---------------- sim = (A . A^T) / 0.07 via bf16 MFMA, fp32 input ----------
// fp32->bf16 conversion in registers per fragment (round-1-verified correct):
// removes the separate convert dispatch. Input is L2/L3-resident (1 MB fp32);
// the 2x fragment-load bytes vs pre-converted bf16 cost ~1 us of L2 traffic,
// less than the dispatch+gap they replace. One wave per 16x16 output tile.
// For C = A.A^T both A-frag (A[m=lane&15][k=quad*8+j]) and B-frag
// (B[k][n]=A[n][k] -> A[n=lane&15][k=quad*8+j]) are one contiguous 32B row
// chunk per lane: no LDS, no transpose. 256 blocks, 4 waves each.
__global__ __launch_bounds__(256) void gemm_fused(const float* __restrict__ A,
                                                  float* __restrict__ S) {
    const int tid = threadIdx.x;
    const int w = tid >> 6, lane = tid & 63;
    const int quad = lane >> 4, r = lane & 15;
    const int m0 = blockIdx.y * 64 + w * 16;   // 4 waves stacked in M
    const int n0 = blockIdx.x * 16;            // shared across waves -> L1 reuse of B
    const float* arow = A + (m0 + r) * DDIM + quad * 8;
    const float* brow = A + (n0 + r) * DDIM + quad * 8;
    ffrag c = {0.f, 0.f, 0.f, 0.f};
#pragma unroll
    for (int k = 0; k < DDIM; k += 32) {
        c = __builtin_amdgcn_mfma_f32_16x16x32_bf16(cvt8(arow + k), cvt8(brow + k),
                                                    c, 0, 0, 0);
    }
    const float sc = 1.0f / 0.07f;
    // C/D layout: row = quad*4 + reg, col = lane&15 (m89-verified mapping)
#pragma unroll
    for (int rg = 0; rg < 4; ++rg)
        S[(m0 + quad * 4 + rg) * BDIM + n0 + r] = c[rg] * sc;
}

__device__ __forceinline__ float softplus_f(float z) {
    // softplus(z) = -log_sigmoid(-z), stable; returns exactly 0 for z = -inf
    return fmaxf(z, 0.0f) + __logf(1.0f + __expf(-fabsf(z)));
}

// ---------------- pairwise softplus loss ----------------
// SPLIT blocks per row. Ballot compaction (2 LDS atomics per wave per round).
// Heavy loop: 4 p-values per outer iter (one ds_read_b128), 4 independent
// accumulator chains for ILP.
// NO contended global atomics: each block stores its partial to a DISTINCT
// address (plain fire-and-forget store). Round-1 evidence: same-cacheline
// return-value atomics + threadfence serialized at ~25 ns each cost ~50 us
// (pair_loss 59.4 us, all pipes idle, Occ 25%). Plain distinct-address
// stores + separate 1-block finalize is the fast structure (round 2).
__global__ __launch_bounds__(256) void pair_loss(const float* __restrict__ S,
                                                 const float* __restrict__ mask,
                                                 const int* __restrict__ sel,
                                                 double* __restrict__ part,
                                                 double* __restrict__ rowpair) {
    const int i = blockIdx.x >> 2;     // row
    const int q = blockIdx.x & 3;      // p-chunk
    const int tid = threadIdx.x;
    if (sel[i] == 0) {                 // sel multiplies both masks
        if (tid == 0) { part[blockIdx.x] = 0.0; if (q == 0) rowpair[i] = 0.0; }
        return;
    }
    __shared__ float sm[BDIM];
    __shared__ __align__(16) float ps[BDIM + 4];
    __shared__ float ns[BDIM];
    __shared__ int cnt[2];
    __shared__ float wsum[4];
    const int lane = tid & 63, wave = tid >> 6;
    if (tid < 2) cnt[tid] = 0;
    for (int p = tid; p < BDIM; p += 256) sm[p] = S[i * BDIM + p];
    __syncthreads();
#pragma unroll
    for (int r = 0; r < 2; ++r) {
        const int p = tid + r * 256;
        const float m = mask[i * BDIM + p];     // exactly 0.0f or 1.0f
        const bool ok  = (p != i);              // logits_mask kills diagonal
        const bool isp = ok && (m != 0.0f);
        const bool isn = ok && (m == 0.0f);
        unsigned long long bp = __ballot(isp);
        unsigned long long bn = __ballot(isn);
        unsigned long long lower = (1ULL << lane) - 1ULL;
        int pbase = 0, nbase = 0;
        if (lane == 0) {
            pbase = atomicAdd(&cnt[0], __popcll(bp));
            nbase = atomicAdd(&cnt[1], __popcll(bn));
        }
        pbase = __shfl(pbase, 0, 64);
        nbase = __shfl(nbase, 0, 64);
        if (isp) ps[pbase + __popcll(bp & lower)] = sm[p];
        if (isn) ns[nbase + __popcll(bn & lower)] = sm[p];
    }
    __syncthreads();
    const int npos = cnt[0], nneg = cnt[1];
    if (tid < 4) ps[npos + tid] = INFINITY;   // pad: softplus(sn - inf) == 0
    __syncthreads();
    // 4-aligned chunk boundaries partitioning [0, npos)
    int p0 = (q == 0) ? 0 : min(npos, ((q * npos) / SPLIT + 3) & ~3);
    int p1 = (q == SPLIT - 1) ? npos : min(npos, (((q + 1) * npos) / SPLIT + 3) & ~3);
    float l0 = 0.f, l1 = 0.f, l2 = 0.f, l3 = 0.f;
    for (int pp = p0; pp < p1; pp += 4) {
        float4 sp = *(const float4*)&ps[pp];
        for (int nn = tid; nn < nneg; nn += 256) {
            float sn = ns[nn];
            l0 += softplus_f(sn - sp.x);
            l1 += softplus_f(sn - sp.y);
            l2 += softplus_f(sn - sp.z);
            l3 += softplus_f(sn - sp.w);
        }
    }
    float local = (l0 + l1) + (l2 + l3);
#pragma unroll
    for (int off = 32; off > 0; off >>= 1) local += __shfl_down(local, off, 64);
    if (lane == 0) wsum[wave] = local;
    __syncthreads();
    if (tid == 0) {
        double tot = (double)wsum[0] + (double)wsum[1] + (double)wsum[2] + (double)wsum[3];
        part[blockIdx.x] = tot;                                  // distinct address
        if (q == 0) rowpair[i] = (double)npos * (double)nneg;    // distinct address
    }
}

// ---------------- final reduction: 2048 + 512 doubles, one block ----------
__global__ __launch_bounds__(256) void finalize(const double* __restrict__ part,
                                                const double* __restrict__ rowpair,
                                                float* __restrict__ out) {
    const int tid = threadIdx.x;
    const int lane = tid & 63, wave = tid >> 6;
    __shared__ double wls[4], wpn[4];
    double ls = 0.0, pn = 0.0;
#pragma unroll
    for (int j = 0; j < NPART / 256; ++j) ls += part[tid + j * 256];
#pragma unroll
    for (int j = 0; j < BDIM / 256; ++j) pn += rowpair[tid + j * 256];
#pragma unroll
    for (int off = 32; off > 0; off >>= 1) {
        ls += __shfl_down(ls, off, 64);
        pn += __shfl_down(pn, off, 64);
    }
    if (lane == 0) { wls[wave] = ls; wpn[wave] = pn; }
    __syncthreads();
    if (tid == 0) {
        double lsum = wls[0] + wls[1] + wls[2] + wls[3];
        double psum = wpn[0] + wpn[1] + wpn[2] + wpn[3];
        double loss = (psum > 0.0) ? lsum / fmax(psum, 1.0) : lsum;
        out[0] = (float)loss;
    }
}

extern "C" void kernel_launch(void* const* d_in, const int* in_sizes, int n_in,
                              void* d_out, int out_size, void* d_ws, size_t ws_size,
                              hipStream_t stream) {
    const float* feat = (const float*)d_in[0];   // (512,1,512) == anchor (512,512)
    const float* mask = (const float*)d_in[1];   // (512,512) fp32 {0,1}
    const int*   sel  = (const int*)d_in[2];     // (512,) bool -> int32
    float* out = (float*)d_out;

    char* ws = (char*)d_ws;
    float* S = (float*)ws;                                   // 1 MB, 16B-aligned
    double* part = (double*)(ws + BDIM * BDIM * sizeof(float));      // 16 KB
    double* rowpair = part + NPART;                                  // 4 KB

    gemm_fused<<<dim3(BDIM / 16, BDIM / 64), 256, 0, stream>>>(feat, S);
    pair_loss<<<NPART, 256, 0, stream>>>(S, mask, sel, part, rowpair);
    finalize<<<1, 256, 0, stream>>>(part, rowpair, out);
}

// Round 4
// 88.424 us; speedup vs baseline: 1.0392x; 1.0392x over previous
//
#include <hip/hip_runtime.h>
#include <hip/hip_bf16.h>
#include <math.h>

#define BDIM 512
#define DDIM 512
#define SPLIT 4     // blocks per row in pair_loss
#define NPART (BDIM * SPLIT)

typedef __attribute__((ext_vector_type(8))) short bfrag;   // 8 bf16 = 4 VGPRs
typedef __attribute__((ext_vector_type(4))) float ffrag;   // 4 fp32 acc

// ---------------- fp32 -> bf16 convert --------
// Kept as a SEPARATE pass (round-3 lesson): fusing the convert into the GEMM
// re-converts every element once per fragment re-read (~32x), adding ~16 VALU
// cycles per 5-cycle MFMA -> GEMM goes VALU-bound, net +2.6 us. Converting
// once per element here costs ~1 us + launch.
__global__ __launch_bounds__(256) void convert_bf16(const float* __restrict__ A,
                                                    __hip_bfloat16* __restrict__ Ab) {
    const int idx = (blockIdx.x * 256 + threadIdx.x) * 4;
    float4 v = *(const float4*)&A[idx];
    union { __hip_bfloat16 h[4]; ushort4 u; } cv;
    cv.h[0] = __float2bfloat16(v.x); cv.h[1] = __float2bfloat16(v.y);
    cv.h[2] = __float2bfloat16(v.z); cv.h[3] = __float2bfloat16(v.w);
    *(ushort4*)&Ab[idx] = cv.u;
}

// ---------------- sim = (A . A^T) / 0.07 via bf16 MFMA ----------------
// One wave per 16x16 output tile; fragments loaded DIRECTLY from global
// (L2-resident, 512 KB). For C = A.A^T both A-frag (A[m=lane&15][k=quad*8+j])
// and B-frag (B[k][n]=A[n][k] -> A[n=lane&15][k=quad*8+j]) are one contiguous
// 16B row chunk per lane: no LDS, no transpose. 256 blocks, 4 waves each.
__global__ __launch_bounds__(256) void gemm_mfma(const __hip_bfloat16* __restrict__ Ab,
                                                 float* __restrict__ S) {
    const int tid = threadIdx.x;
    const int w = tid >> 6, lane = tid & 63;
    const int quad = lane >> 4, r = lane & 15;
    const int m0 = blockIdx.y * 64 + w * 16;   // 4 waves stacked in M
    const int n0 = blockIdx.x * 16;            // shared across waves -> L1 reuse of B
    const __hip_bfloat16* arow = Ab + (m0 + r) * DDIM + quad * 8;
    const __hip_bfloat16* brow = Ab + (n0 + r) * DDIM + quad * 8;
    ffrag acc = {0.f, 0.f, 0.f, 0.f};
#pragma unroll
    for (int k = 0; k < DDIM; k += 32) {
        bfrag af = *(const bfrag*)(arow + k);
        bfrag bf = *(const bfrag*)(brow + k);
        acc = __builtin_amdgcn_mfma_f32_16x16x32_bf16(af, bf, acc, 0, 0, 0);
    }
    const float sc = 1.0f / 0.07f;
    // C/D layout: row = quad*4 + reg, col = lane&15 (m89-verified mapping)
#pragma unroll
    for (int rg = 0; rg < 4; ++rg)
        S[(m0 + quad * 4 + rg) * BDIM + n0 + r] = acc[rg] * sc;
}

__device__ __forceinline__ float softplus_f(float z) {
    // softplus(z) = -log_sigmoid(-z), stable; returns exactly 0 for z = -inf
    return fmaxf(z, 0.0f) + __logf(1.0f + __expf(-fabsf(z)));
}

// ---------------- pairwise softplus loss ----------------
// SPLIT blocks per row. Ballot compaction (2 LDS atomics per wave per round).
// Heavy loop: 4 p-values per outer iter (one ds_read_b128), 4 independent
// accumulator chains for ILP.
// NO contended global atomics: each block stores its partial to a DISTINCT
// address (plain fire-and-forget store). Round-1 evidence: same-cacheline
// return-value atomics + threadfence serialized at ~25 ns each cost ~50 us
// (pair_loss 59.4 us, all pipes idle, Occ 25%). Plain distinct-address
// stores + separate 1-block finalize is the fast structure (round 2).
__global__ __launch_bounds__(256) void pair_loss(const float* __restrict__ S,
                                                 const float* __restrict__ mask,
                                                 const int* __restrict__ sel,
                                                 double* __restrict__ part,
                                                 double* __restrict__ rowpair) {
    const int i = blockIdx.x >> 2;     // row
    const int q = blockIdx.x & 3;      // p-chunk
    const int tid = threadIdx.x;
    if (sel[i] == 0) {                 // sel multiplies both masks
        if (tid == 0) { part[blockIdx.x] = 0.0; if (q == 0) rowpair[i] = 0.0; }
        return;
    }
    __shared__ float sm[BDIM];
    __shared__ __align__(16) float ps[BDIM + 4];
    __shared__ float ns[BDIM];
    __shared__ int cnt[2];
    __shared__ float wsum[4];
    const int lane = tid & 63, wave = tid >> 6;
    if (tid < 2) cnt[tid] = 0;
    for (int p = tid; p < BDIM; p += 256) sm[p] = S[i * BDIM + p];
    __syncthreads();
#pragma unroll
    for (int r = 0; r < 2; ++r) {
        const int p = tid + r * 256;
        const float m = mask[i * BDIM + p];     // exactly 0.0f or 1.0f
        const bool ok  = (p != i);              // logits_mask kills diagonal
        const bool isp = ok && (m != 0.0f);
        const bool isn = ok && (m == 0.0f);
        unsigned long long bp = __ballot(isp);
        unsigned long long bn = __ballot(isn);
        unsigned long long lower = (1ULL << lane) - 1ULL;
        int pbase = 0, nbase = 0;
        if (lane == 0) {
            pbase = atomicAdd(&cnt[0], __popcll(bp));
            nbase = atomicAdd(&cnt[1], __popcll(bn));
        }
        pbase = __shfl(pbase, 0, 64);
        nbase = __shfl(nbase, 0, 64);
        if (isp) ps[pbase + __popcll(bp & lower)] = sm[p];
        if (isn) ns[nbase + __popcll(bn & lower)] = sm[p];
    }
    __syncthreads();
    const int npos = cnt[0], nneg = cnt[1];
    if (tid < 4) ps[npos + tid] = INFINITY;   // pad: softplus(sn - inf) == 0
    __syncthreads();
    // 4-aligned chunk boundaries partitioning [0, npos)
    int p0 = (q == 0) ? 0 : min(npos, ((q * npos) / SPLIT + 3) & ~3);
    int p1 = (q == SPLIT - 1) ? npos : min(npos, (((q + 1) * npos) / SPLIT + 3) & ~3);
    float l0 = 0.f, l1 = 0.f, l2 = 0.f, l3 = 0.f;
    for (int pp = p0; pp < p1; pp += 4) {
        float4 sp = *(const float4*)&ps[pp];
        for (int nn = tid; nn < nneg; nn += 256) {
            float sn = ns[nn];
            l0 += softplus_f(sn - sp.x);
            l1 += softplus_f(sn - sp.y);
            l2 += softplus_f(sn - sp.z);
            l3 += softplus_f(sn - sp.w);
        }
    }
    float local = (l0 + l1) + (l2 + l3);
#pragma unroll
    for (int off = 32; off > 0; off >>= 1) local += __shfl_down(local, off, 64);
    if (lane == 0) wsum[wave] = local;
    __syncthreads();
    if (tid == 0) {
        double tot = (double)wsum[0] + (double)wsum[1] + (double)wsum[2] + (double)wsum[3];
        part[blockIdx.x] = tot;                                  // distinct address
        if (q == 0) rowpair[i] = (double)npos * (double)nneg;    // distinct address
    }
}

// ---------------- final reduction: 2048 + 512 doubles, one block ----------
__global__ __launch_bounds__(256) void finalize(const double* __restrict__ part,
                                                const double* __restrict__ rowpair,
                                                float* __restrict__ out) {
    const int tid = threadIdx.x;
    const int lane = tid & 63, wave = tid >> 6;
    __shared__ double wls[4], wpn[4];
    double ls = 0.0, pn = 0.0;
#pragma unroll
    for (int j = 0; j < NPART / 256; ++j) ls += part[tid + j * 256];
#pragma unroll
    for (int j = 0; j < BDIM / 256; ++j) pn += rowpair[tid + j * 256];
#pragma unroll
    for (int off = 32; off > 0; off >>= 1) {
        ls += __shfl_down(ls, off, 64);
        pn += __shfl_down(pn, off, 64);
    }
    if (lane == 0) { wls[wave] = ls; wpn[wave] = pn; }
    __syncthreads();
    if (tid == 0) {
        double lsum = wls[0] + wls[1] + wls[2] + wls[3];
        double psum = wpn[0] + wpn[1] + wpn[2] + wpn[3];
        double loss = (psum > 0.0) ? lsum / fmax(psum, 1.0) : lsum;
        out[0] = (float)loss;
    }
}

extern "C" void kernel_launch(void* const* d_in, const int* in_sizes, int n_in,
                              void* d_out, int out_size, void* d_ws, size_t ws_size,
                              hipStream_t stream) {
    const float* feat = (const float*)d_in[0];   // (512,1,512) == anchor (512,512)
    const float* mask = (const float*)d_in[1];   // (512,512) fp32 {0,1}
    const int*   sel  = (const int*)d_in[2];     // (512,) bool -> int32
    float* out = (float*)d_out;

    char* ws = (char*)d_ws;
    float* S = (float*)ws;                                   // 1 MB, 16B-aligned
    double* part = (double*)(ws + BDIM * BDIM * sizeof(float));      // 16 KB
    double* rowpair = part + NPART;                                  // 4 KB
    __hip_bfloat16* Ab = (__hip_bfloat16*)(ws + BDIM * BDIM * 4 + 32 * 1024);  // 512 KB

    convert_bf16<<<BDIM * DDIM / 1024, 256, 0, stream>>>(feat, Ab);
    gemm_mfma<<<dim3(BDIM / 16, BDIM / 64), 256, 0, stream>>>(Ab, S);
    pair_loss<<<NPART, 256, 0, stream>>>(S, mask, sel, part, rowpair);
    finalize<<<1, 256, 0, stream>>>(part, rowpair, out);
}